// Round 11
// baseline (168.535 us; speedup 1.0000x reference)
//
#include <hip/hip_runtime.h>

// Problem constants
#define HW    128
#define PW    130          // padded stream pitch (1-px zero border)
#define NCELL 16
#define ABUF_PER_CELL 23040   // 3 slots * 5 chunks * 4 quads * 48 co * 8
#define ABUF_TOTAL (NCELL * ABUF_PER_CELL)          // 368640
#define NSTREAMS 15
#define BORDER_PX 516                                // 130*130 - 128*128
#define BORDER_TASKS (NSTREAMS * 8 * BORDER_PX * 2)  // 123840 half8-stores

typedef _Float16 half8 __attribute__((ext_vector_type(8)));
typedef _Float16 half4 __attribute__((ext_vector_type(4)));
typedef float    f32x4 __attribute__((ext_vector_type(4)));

// async global->LDS, 16 B per lane; LDS dest = wave-uniform base + lane*16
#define GLD_LDS(gp, lp) __builtin_amdgcn_global_load_lds( \
    (const __attribute__((address_space(1))) void*)(gp),  \
    (__attribute__((address_space(3))) void*)(lp), 16, 0, 0)

// ---------------------------------------------------------------------------
// r29 = EXACT r27 REVERT (session best, 162.8us). Final state.
//
// Validated wins: r18 border-ring armor (-10); r21 counted-vmcnt staging
// pipeline (-22); r27 ROWS=8 full-residency singles (-2.7).
// Falsified levers (all measured): ILP narrowing / drain splitting (r22,
// +5); head fusion inline/mega/fine (r23/r24/r28, +5 each — the ~4us
// serialized head node is cheaper than any in-stage substitute); direct-B
// without LDS staging (r26, +10 — staging is load-bearing; L2 per-XCD
// slice BW, not aggregate, is the relevant ceiling); VGPR-estimate-driven
// edits (r22 — compiler liveness beats hand counts).
// Remaining gap vs ~52us HBM floor is the 10-stage dependency chain's
// serialized launch+staging latency; legal escape routes exhausted
// (r14 cross-XCD dataflow, r17 cooperative launch, r23/24/28 fusion).
//
// Fused head kernel (r18, validated): weight prep + border-ring zero.
// Abuf: [cell][slot3][chunk5][quad4][co48][j8]; g = chunk*4+quad ->
// (kh=g/6, kw=(g%6)/2, cg=g&1), ci = slot*16+cg*8+j; g>=18 -> 0.
// Border ring (1.98 MB): only stream region read-but-never-written per
// call (r19: replays bit-identically; r11's ghost was the poisoned ring).
// ---------------------------------------------------------------------------
__global__ void prep_w_border_k(const float* __restrict__ W,
                                _Float16* __restrict__ Abuf,
                                _Float16* __restrict__ sbase) {
    int idx = blockIdx.x * 256 + threadIdx.x;
    if (idx < ABUF_TOTAL) {
        int j = idx & 7;
        int t = idx >> 3;
        int co = t % 48;   t /= 48;
        int quad = t & 3;  t >>= 2;
        int chunk = t % 5; t /= 5;
        int slot = t % 3;  t /= 3;
        int cell = t;
        int g = chunk * 4 + quad;
        float v = 0.f;
        if (g < 18) {
            int kh = g / 6, r6 = g % 6;
            int kw = r6 >> 1, cg = r6 & 1;
            int ci = slot * 16 + cg * 8 + j;
            v = W[((size_t)(cell * 48 + co) * 48 + ci) * 9 + kh * 3 + kw];
        }
        Abuf[idx] = (_Float16)v;
        return;
    }
    int t = idx - ABUF_TOTAL;
    if (t >= BORDER_TASKS) return;
    int h  = t & 1;                 // which half8 of the 16-ch pixel
    int pb = t >> 1;
    int p  = pb % BORDER_PX;
    int bb = pb / BORDER_PX;        // buffer*8 + batch (buffers contiguous)
    int y, x;
    if (p < 260) {                  // top + bottom rows, full 130 px
        y = (p < 130) ? 0 : (PW - 1);
        x = p - ((p < 130) ? 0 : 130);
    } else {                        // left/right columns, rows 1..128
        int e = p - 260;
        y = 1 + (e >> 1);
        x = (e & 1) ? (PW - 1) : 0;
    }
    half8 z = {};
    *(half8*)(sbase + (size_t)bb * (PW * PW * 16)
              + ((size_t)y * PW + x) * 16 + h * 8) = z;
}

// Per-cell I/O descriptor. Streams: fp16 NHWC, 130x130 pitch, zero border.
struct CellIO {
    const _Float16* in0; const _Float16* in1; const _Float16* in2;
    const _Float16* Ac; const float* bc;
    _Float16* o0; _Float16* o1; _Float16* o2;
    float* fout;
};

// ---------------------------------------------------------------------------
// One grid-cell conv body: slot-major implicit GEMM, fp16 A x fp16 B, fp32
// accumulate (validated r11-16). ROWS = tile height (16 or 8); width 16.
//
// LDS layout (r16, conflict-free): unit u = (iy*2 + cg)*18 + ix, 8 halfs per
// unit = channels [8cg, 8cg+8) of halo pixel (iy, ix). B-reads for a quad hit
// 16 CONSECUTIVE units (16 B apart) -> 2 bank-wraps -> conflict-free.
// Slot padded to KBLK*64 units (ROWS=16: 648->704, 11 DMA rounds; ROWS=8:
// 360->384, 6 rounds). Pad units never read; worst-case global over-read
// past the LAST stream buffer: 7.8 KB (ROWS=16) / 4.1 KB (ROWS=8) —
// inside ws slack.
//
// r21 PIPELINE (preserved):
//   preload bias + s0 A-frags c0..2 (OLDEST in vmcnt queue -> covered by
//   the counted wait for free) -> stage(0) -> stage(1..) ->
//   s_waitcnt vmcnt((NIN-1)*C) + s_barrier   [own+all slot0 retired]
//   -> compute s0 c0..2 -> __syncthreads() [full drain, slot1 needed;
//      vmcnt retires IN-ORDER so deeper drain-splitting is a no-op]
//   -> s1(,s2) all chunks -> s0 c3,c4 last.
// s_setprio(1) around each MFMA cluster. Bh[NT] wide.
// Per-wave DMA count per slot C: ROWS=16: wv==3?2:3; ROWS=8: wv<2?2:1.
// ---------------------------------------------------------------------------
template<int LIVE, int NIN, bool FIN, bool XIN, int ROWS>
__device__ __forceinline__ void cell_body(const CellIO& P, int b, _Float16* xh,
                                          const float* xsrc)
{
    constexpr int NT   = ROWS / 4;             // rows per wave
    constexpr int KBLK = (ROWS == 16) ? 11 : 6; // 64-unit DMA rounds per slot
    constexpr int SLTH = KBLK * 512;            // halfs per LDS slot
    constexpr int HR   = ROWS + 2;              // halo rows

    const int tid = threadIdx.x;
    const int bx = blockIdx.x, by = blockIdx.y;
    const int x0 = bx * 16, y0 = by * ROWS;
    const int lane = tid & 63, wv = tid >> 6;
    const int n = lane & 15, quad = lane >> 4;
    const int py0 = wv * NT;

    float bv[3][4];      // preloaded bias (!XIN)
    half8 a0[3][3];      // preloaded slot0 A-frags, chunks 0..2 (!XIN)

    if constexpr (XIN) {
        // 16*HR row-tasks (ci16, iy in halo): fp32 NCHW, bounds-checked
        for (int task = tid; task < 16 * HR; task += 256) {
            int ci = task / HR, iy = task - (task / HR) * HR;
            float v[18];
#pragma unroll
            for (int ix = 0; ix < 18; ++ix) v[ix] = 0.f;
            int gy = y0 + iy - 1;
            if ((unsigned)gy < (unsigned)HW) {
                const float* rp = xsrc + (((size_t)b * 16 + ci) * HW + gy) * HW + x0;
                f32x4 q0 = *(const f32x4*)(rp);
                f32x4 q1 = *(const f32x4*)(rp + 4);
                f32x4 q2 = *(const f32x4*)(rp + 8);
                f32x4 q3 = *(const f32x4*)(rp + 12);
#pragma unroll
                for (int j = 0; j < 4; ++j) {
                    v[1 + j] = q0[j]; v[5 + j] = q1[j];
                    v[9 + j] = q2[j]; v[13 + j] = q3[j];
                }
                if (x0 > 0)       v[0]  = rp[-1];
                if (x0 < HW - 16) v[17] = rp[16];
            }
            int cg = ci >> 3, cj = ci & 7;
#pragma unroll
            for (int ix = 0; ix < 18; ++ix)
                xh[(((iy * 2 + cg) * 18) + ix) * 8 + cj] = (_Float16)v[ix];
        }
        __syncthreads();
    } else {
        const _Float16* const ins[3] = {P.in0, P.in1, P.in2};
        auto stage = [&](int s) {
            // tile halo origin in padded coords = (by*ROWS, bx*16)
            const _Float16* src = ins[s] + (size_t)b * (PW * PW * 16)
                                 + ((size_t)y0 * PW + bx * 16) * 16;
            _Float16* base = xh + s * SLTH;
#pragma unroll
            for (int k = 0; k < 3; ++k) {
                int kk = wv + k * 4;
                if (kk < KBLK) {            // wave-uniform
                    int u = kk * 64 + lane;
                    int iy = u / 36, r36 = u - iy * 36;
                    int cg = r36 / 18, ix = r36 - cg * 18;
                    GLD_LDS(src + (iy * PW + ix) * 16 + cg * 8, base + kk * 512);
                }
            }
        };
        // Preload FIRST: oldest VMEM ops -> counted DMA wait covers them.
#pragma unroll
        for (int cot = 0; cot < 3; ++cot) {
            if (!(LIVE & (1 << cot))) continue;
#pragma unroll
            for (int r = 0; r < 4; ++r) bv[cot][r] = P.bc[cot * 16 + quad * 4 + r];
        }
        {
            const _Float16* As0 = P.Ac + quad * 384 + n * 8;
#pragma unroll
            for (int c = 0; c < 3; ++c)
#pragma unroll
                for (int cot = 0; cot < 3; ++cot) {
                    if (!(LIVE & (1 << cot))) continue;
                    a0[c][cot] = *(const half8*)(As0 + c * 1536 + cot * 128);
                }
        }
        asm volatile("" ::: "memory");   // keep preloads ahead of the DMAs
        stage(0);
        if constexpr (NIN >= 2) {
            asm volatile("" ::: "memory");
#pragma unroll
            for (int s = 1; s < NIN; ++s) stage(s);
            // own slot0 DMA retired when <= (NIN-1)*C outstanding
            if constexpr (ROWS == 16) {
                if (wv == 3) asm volatile("s_waitcnt vmcnt(%0)" :: "n"((NIN - 1) * 2) : "memory");
                else         asm volatile("s_waitcnt vmcnt(%0)" :: "n"((NIN - 1) * 3) : "memory");
            } else {
                if (wv < 2)  asm volatile("s_waitcnt vmcnt(%0)" :: "n"((NIN - 1) * 2) : "memory");
                else         asm volatile("s_waitcnt vmcnt(%0)" :: "n"((NIN - 1) * 1) : "memory");
            }
            __builtin_amdgcn_s_barrier();   // -> all waves' slot0 retired
            asm volatile("" ::: "memory");
        } else {
            __syncthreads();
        }
    }

    // Per-chunk B-read base unit. Dead groups (g>=18) -> g=0 (A zero there).
    int base_c[5];
#pragma unroll
    for (int c = 0; c < 5; ++c) {
        int g = c * 4 + quad;
        if (g >= 18) g = 0;
        int kh = g / 6, r6 = g % 6;
        int kw = r6 >> 1, cg = r6 & 1;
        base_c[c] = ((py0 + kh) * 2 + cg) * 18 + n + kw;
    }

    // acc[cot][nt]: co = cot*16 + quad*4 + r, pixel (y0+py0+nt, x0+n)
    constexpr bool PIPE = (!XIN) && (NIN >= 2);
    f32x4 acc[3][NT];
#pragma unroll
    for (int cot = 0; cot < 3; ++cot) {
        if (!(LIVE & (1 << cot))) continue;
#pragma unroll
        for (int r = 0; r < 4; ++r) {
            float bvv = XIN ? P.bc[cot * 16 + quad * 4 + r] : bv[cot][r];
#pragma unroll
            for (int nt = 0; nt < NT; ++nt) acc[cot][nt][r] = bvv;
        }
    }

    // ---- K loop: flattened NIN*5 chunk schedule, fully unrolled ----
    // PIPE order: s0c0..2 | barrier | s1(,s2) all | s0c3,c4.
    constexpr int NC = NIN * 5;
#pragma unroll
    for (int i = 0; i < NC; ++i) {
        int s, c;
        if constexpr (PIPE) {
            if (i < 3)                        { s = 0; c = i; }
            else if (i < 3 + 5 * (NIN - 1))   { s = 1 + (i - 3) / 5; c = (i - 3) % 5; }
            else                              { s = 0; c = i - 5 * (NIN - 1); }
        } else { s = i / 5; c = i % 5; }
        if (PIPE && i == 3) __syncthreads();   // slots 1.. ready (full drain)

        const _Float16* sxh = xh + s * (XIN ? 0 : ((ROWS == 16) ? 5632 : 3072));
        half8 Bh[NT];
#pragma unroll
        for (int nt = 0; nt < NT; ++nt)
            Bh[nt] = *(const half8*)(sxh + (base_c[c] + nt * 36) * 8);
        const _Float16* Ab = P.Ac + (size_t)(s * 5 + c) * 1536 + quad * 384 + n * 8;
        half8 ah[3];
#pragma unroll
        for (int cot = 0; cot < 3; ++cot) {
            if (!(LIVE & (1 << cot))) continue;
            if (!XIN && s == 0 && c < 3) ah[cot] = a0[c][cot];
            else                         ah[cot] = *(const half8*)(Ab + cot * 128);
        }
        __builtin_amdgcn_s_setprio(1);
#pragma unroll
        for (int cot = 0; cot < 3; ++cot) {
            if (!(LIVE & (1 << cot))) continue;
#pragma unroll
            for (int nt = 0; nt < NT; ++nt)
                acc[cot][nt] = __builtin_amdgcn_mfma_f32_16x16x32_f16(ah[cot], Bh[nt], acc[cot][nt], 0, 0, 0);
        }
        __builtin_amdgcn_s_setprio(0);
    }

    // ---- epilogue ----
    if constexpr (FIN) {
        // final cell: fp32 NCHW scatter to d_out (validated path)
#pragma unroll
        for (int nt = 0; nt < NT; ++nt) {
            int y = y0 + py0 + nt, xg = x0 + n;
#pragma unroll
            for (int r = 0; r < 4; ++r) {
                float vv = acc[0][nt][r];
                P.fout[(((size_t)b * 16 + quad * 4 + r) * HW + y) * HW + xg] = vv > 0.f ? vv : 0.f;
            }
        }
    } else {
        // fp16 NHWC stores into padded interior (+1,+1)
        _Float16* const outs[3] = {P.o0, P.o1, P.o2};
#pragma unroll
        for (int cot = 0; cot < 3; ++cot) {
            if (!(LIVE & (1 << cot))) continue;
            _Float16* op = outs[cot] + (size_t)b * (PW * PW * 16);
#pragma unroll
            for (int nt = 0; nt < NT; ++nt) {
                int y = y0 + py0 + nt;
                half4 hv;
#pragma unroll
                for (int r = 0; r < 4; ++r) {
                    float vv = acc[cot][nt][r];
                    hv[r] = (_Float16)(vv > 0.f ? vv : 0.f);
                }
                *(half4*)(op + ((size_t)(y + 1) * PW + x0 + n + 1) * 16 + quad * 4) = hv;
            }
        }
    }
}

// ---------------------------------------------------------------------------
// Stage kernel: one or two independent cells per launch. blockIdx.z < 8 ->
// cell 0 (batch z), z >= 8 -> cell 1 (batch z-8, always ROWS=16). R0 = tile
// height for cell 0. LDS sized for the max of both paths.
// ---------------------------------------------------------------------------
template<int L0, int N0, int L1, int N1, bool FIN, bool XIN, int R0>
__global__ __launch_bounds__(256, 4) void cell_k(CellIO P0, CellIO P1,
                                                 const float* xsrc) {
    constexpr int slotR = (R0 == 16) ? 5632 : 3072;
    constexpr int ldsA  = XIN ? ((R0 + 2) * 2 * 18 * 8) : (N0 * slotR);
    constexpr int ldsB  = (L1 > 0) ? (N1 * 5632) : 0;
    constexpr int LDSH  = (ldsA > ldsB) ? ldsA : ldsB;
    __shared__ __align__(16) _Float16 xh[LDSH];
    int b = blockIdx.z & 7;
    if constexpr (L1 > 0) {
        if (blockIdx.z >= 8) { cell_body<L1, N1, false, false, 16>(P1, b, xh, nullptr); return; }
    }
    cell_body<L0, N0, FIN, XIN, R0>(P0, b, xh, xsrc);
}

// ---------------------------------------------------------------------------
// Orchestration: anti-diagonal stage schedule s = 2*col + row (validated r5;
// depth-10 is the exact dependency-graph longest path — launch-minimal).
// Buffers: padded 130x130 fp16 NHWC (4.33 MB): R[colpar][row] x8, U[1..3] x3,
// D[2][2] x4. Cell (0,0) reads fp32 x directly.
//
// Structural plateau notes: cross-XCD flag dataflow (r14) and cooperative
// launch (r17) fail; head-fusion fails all three ways (r23 inline, r24
// mega, r28 fine-backfill: ~+5us each); direct-B without LDS staging
// +10us (r26). 10 stage launches + 1 head node is the legal minimum.
//
// DETERMINISM ARMOR (r18/r19): harness re-poisons d_ws 0xAA each call; the
// border ring is the only stream region read-but-never-written per call, so
// ring-only zeroing (fused into the head launch) keeps replay bit-identical
// (r19 validated). Staging over-DMA reads at most 7.8 KB (ROWS=16) / 4.1 KB
// (ROWS=8) past the last stream buffer — inside ws slack (poisoned, unread).
// ---------------------------------------------------------------------------
extern "C" void kernel_launch(void* const* d_in, const int* in_sizes, int n_in,
                              void* d_out, int out_size, void* d_ws, size_t ws_size,
                              hipStream_t stream) {
    const float* x  = (const float*)d_in[0];   // [8,16,128,128]
    const float* W  = (const float*)d_in[1];   // [4,4,48,48,3,3]
    const float* bi = (const float*)d_in[2];   // [4,4,48]
    float* out = (float*)d_out;                // [8,16,128,128]

    _Float16* Abuf = (_Float16*)d_ws;
    const size_t abytes = (size_t)NCELL * ABUF_PER_CELL * 2;   // 0.74 MB
    _Float16* q = (_Float16*)((char*)d_ws + abytes);
    _Float16* sbase = q;                                       // stream region base
    const size_t S = (size_t)8 * PW * PW * 16;                 // halfs/buffer

    _Float16 *R[2][4], *U[4], *D[2][2];
    for (int pa = 0; pa < 2; ++pa)
        for (int r = 0; r < 4; ++r) { R[pa][r] = q; q += S; }
    U[0] = nullptr;
    for (int r = 1; r < 4; ++r) { U[r] = q; q += S; }
    D[0][0] = q; q += S; D[0][1] = q; q += S;
    D[1][0] = q; q += S; D[1][1] = q; q += S;

    // Fused head launch: weight prep + border-ring zero
    hipLaunchKernelGGL(prep_w_border_k,
                       dim3((ABUF_TOTAL + BORDER_TASKS + 255) / 256),
                       dim3(256), 0, stream, W, Abuf, sbase);

    auto mkio = [&](int c, int r) -> CellIO {
        CellIO io{};
        if (c == 0) {
            io.in0 = (r == 0) ? nullptr : D[0][(r - 1) & 1];   // r==0: XIN
        } else {
            io.in0 = R[(c - 1) & 1][r];
            if (r == 0)      io.in1 = U[1];
            else if (r == 3) io.in1 = D[c & 1][0];
            else { io.in1 = U[r + 1]; io.in2 = D[c & 1][(r - 1) & 1]; }
        }
        if (c < 3) {
            io.o0 = R[c & 1][r];
            if (r > 0) io.o1 = U[r];
            if (r < 3) io.o2 = D[c & 1][r & 1];
        } else {
            if (r < 3) io.o2 = D[1][r & 1];
            else       io.fout = out;
        }
        io.Ac = Abuf + (size_t)(c * 4 + r) * ABUF_PER_CELL;
        io.bc = bi + (size_t)(c * 4 + r) * 48;
        return io;
    };

    dim3 blk(256), g2(8, 8, 16), g8(8, 16, 8);
#define ONEX(c, r)       do { CellIO a = mkio(c, r); \
    hipLaunchKernelGGL((cell_k<5, 1, 0, 0, false, true, 8>), g8, blk, 0, stream, a, a, x); } while (0)
#define ONE(L, N, c, r)  do { CellIO a = mkio(c, r); \
    hipLaunchKernelGGL((cell_k<L, N, 0, 0, false, false, 8>), g8, blk, 0, stream, a, a, x); } while (0)
#define ONEF(c, r)       do { CellIO a = mkio(c, r); \
    hipLaunchKernelGGL((cell_k<1, 2, 0, 0, true, false, 8>), g8, blk, 0, stream, a, a, x); } while (0)
#define TWO(L0, N0, c0, r0, L1, N1, c1, r1) do { \
    CellIO a = mkio(c0, r0), bb2 = mkio(c1, r1); \
    hipLaunchKernelGGL((cell_k<L0, N0, L1, N1, false, false, 16>), g2, blk, 0, stream, a, bb2, x); } while (0)

    ONEX(0, 0);
    ONE(7, 1, 0, 1);
    TWO(7, 1, 0, 2,  5, 2, 1, 0);
    TWO(3, 1, 0, 3,  7, 3, 1, 1);
    TWO(7, 3, 1, 2,  5, 2, 2, 0);
    TWO(3, 2, 1, 3,  7, 3, 2, 1);
    TWO(7, 3, 2, 2,  4, 2, 3, 0);
    TWO(3, 2, 2, 3,  4, 3, 3, 1);
    ONE(4, 3, 3, 2);
    ONEF(3, 3);
#undef ONEX
#undef ONE
#undef ONEF
#undef TWO
}

// Round 12
// 162.590 us; speedup vs baseline: 1.0366x; 1.0366x over previous
//
#include <hip/hip_runtime.h>

// Problem constants
#define HW    128
#define PW    130          // padded stream pitch (1-px zero border)
#define NCELL 16
#define ABUF_PER_CELL 23040   // 3 slots * 5 chunks * 4 quads * 48 co * 8
#define ABUF_TOTAL (NCELL * ABUF_PER_CELL)          // 368640
#define NSTREAMS 15
#define BORDER_PX 516                                // 130*130 - 128*128
#define BORDER_TASKS (NSTREAMS * 8 * BORDER_PX * 2)  // 123840 half8-stores

typedef _Float16 half8 __attribute__((ext_vector_type(8)));
typedef _Float16 half4 __attribute__((ext_vector_type(4)));
typedef float    f32x4 __attribute__((ext_vector_type(4)));

// async global->LDS, 16 B per lane; LDS dest = wave-uniform base + lane*16
#define GLD_LDS(gp, lp) __builtin_amdgcn_global_load_lds( \
    (const __attribute__((address_space(1))) void*)(gp),  \
    (__attribute__((address_space(3))) void*)(lp), 16, 0, 0)

// ---------------------------------------------------------------------------
// r30 = FINAL: byte-identical r27/r29 (session-best structure).
//
// Session ledger (measured):
//   wins: r18 border-ring armor (-10); r21 counted-vmcnt staging pipeline
//   (-22); r27 ROWS=8 singles (within noise, kept: best single sample).
//   falsified: ILP narrowing / drain splitting (r22 +5); head fusion
//   inline/mega/fine (r23/r24/r28, +5 each); direct-B without LDS staging
//   (r26 +10 — staging is load-bearing; per-XCD L2 slice BW is the
//   relevant ceiling); VGPR-estimate-driven edits (compiler liveness
//   beats hand counts).
//   noise band: +-3us on identical source (r27: 162.8/168.5; r21: 164.7/
//   165.5) — single-run deltas <6us are unmeasurable here.
// Structural constraint: depth-10 launch chain (exact DAG longest path) x
// (launch + staging latency at 16 waves/CU; LDS 33.8KB and ~128 VGPR both
// cap there). Escape mechanisms all benched and rejected (r14 cross-XCD
// dataflow, r17 cooperative launch, r23/24/28 fusion, r26 no-staging).
//
// Fused head kernel (r18, validated): weight prep + border-ring zero.
// Abuf: [cell][slot3][chunk5][quad4][co48][j8]; g = chunk*4+quad ->
// (kh=g/6, kw=(g%6)/2, cg=g&1), ci = slot*16+cg*8+j; g>=18 -> 0.
// Border ring (1.98 MB): only stream region read-but-never-written per
// call (r19: replays bit-identically; r11's ghost was the poisoned ring).
// ---------------------------------------------------------------------------
__global__ void prep_w_border_k(const float* __restrict__ W,
                                _Float16* __restrict__ Abuf,
                                _Float16* __restrict__ sbase) {
    int idx = blockIdx.x * 256 + threadIdx.x;
    if (idx < ABUF_TOTAL) {
        int j = idx & 7;
        int t = idx >> 3;
        int co = t % 48;   t /= 48;
        int quad = t & 3;  t >>= 2;
        int chunk = t % 5; t /= 5;
        int slot = t % 3;  t /= 3;
        int cell = t;
        int g = chunk * 4 + quad;
        float v = 0.f;
        if (g < 18) {
            int kh = g / 6, r6 = g % 6;
            int kw = r6 >> 1, cg = r6 & 1;
            int ci = slot * 16 + cg * 8 + j;
            v = W[((size_t)(cell * 48 + co) * 48 + ci) * 9 + kh * 3 + kw];
        }
        Abuf[idx] = (_Float16)v;
        return;
    }
    int t = idx - ABUF_TOTAL;
    if (t >= BORDER_TASKS) return;
    int h  = t & 1;                 // which half8 of the 16-ch pixel
    int pb = t >> 1;
    int p  = pb % BORDER_PX;
    int bb = pb / BORDER_PX;        // buffer*8 + batch (buffers contiguous)
    int y, x;
    if (p < 260) {                  // top + bottom rows, full 130 px
        y = (p < 130) ? 0 : (PW - 1);
        x = p - ((p < 130) ? 0 : 130);
    } else {                        // left/right columns, rows 1..128
        int e = p - 260;
        y = 1 + (e >> 1);
        x = (e & 1) ? (PW - 1) : 0;
    }
    half8 z = {};
    *(half8*)(sbase + (size_t)bb * (PW * PW * 16)
              + ((size_t)y * PW + x) * 16 + h * 8) = z;
}

// Per-cell I/O descriptor. Streams: fp16 NHWC, 130x130 pitch, zero border.
struct CellIO {
    const _Float16* in0; const _Float16* in1; const _Float16* in2;
    const _Float16* Ac; const float* bc;
    _Float16* o0; _Float16* o1; _Float16* o2;
    float* fout;
};

// ---------------------------------------------------------------------------
// One grid-cell conv body: slot-major implicit GEMM, fp16 A x fp16 B, fp32
// accumulate (validated r11-16). ROWS = tile height (16 or 8); width 16.
//
// LDS layout (r16, conflict-free): unit u = (iy*2 + cg)*18 + ix, 8 halfs per
// unit = channels [8cg, 8cg+8) of halo pixel (iy, ix). B-reads for a quad hit
// 16 CONSECUTIVE units (16 B apart) -> 2 bank-wraps -> conflict-free.
// Slot padded to KBLK*64 units (ROWS=16: 648->704, 11 DMA rounds; ROWS=8:
// 360->384, 6 rounds). Pad units never read; worst-case global over-read
// past the LAST stream buffer: 7.8 KB (ROWS=16) / 4.1 KB (ROWS=8) —
// inside ws slack.
//
// r21 PIPELINE (preserved):
//   preload bias + s0 A-frags c0..2 (OLDEST in vmcnt queue -> covered by
//   the counted wait for free) -> stage(0) -> stage(1..) ->
//   s_waitcnt vmcnt((NIN-1)*C) + s_barrier   [own+all slot0 retired]
//   -> compute s0 c0..2 -> __syncthreads() [full drain, slot1 needed;
//      vmcnt retires IN-ORDER so deeper drain-splitting is a no-op]
//   -> s1(,s2) all chunks -> s0 c3,c4 last.
// s_setprio(1) around each MFMA cluster. Bh[NT] wide.
// Per-wave DMA count per slot C: ROWS=16: wv==3?2:3; ROWS=8: wv<2?2:1.
// ---------------------------------------------------------------------------
template<int LIVE, int NIN, bool FIN, bool XIN, int ROWS>
__device__ __forceinline__ void cell_body(const CellIO& P, int b, _Float16* xh,
                                          const float* xsrc)
{
    constexpr int NT   = ROWS / 4;             // rows per wave
    constexpr int KBLK = (ROWS == 16) ? 11 : 6; // 64-unit DMA rounds per slot
    constexpr int SLTH = KBLK * 512;            // halfs per LDS slot
    constexpr int HR   = ROWS + 2;              // halo rows

    const int tid = threadIdx.x;
    const int bx = blockIdx.x, by = blockIdx.y;
    const int x0 = bx * 16, y0 = by * ROWS;
    const int lane = tid & 63, wv = tid >> 6;
    const int n = lane & 15, quad = lane >> 4;
    const int py0 = wv * NT;

    float bv[3][4];      // preloaded bias (!XIN)
    half8 a0[3][3];      // preloaded slot0 A-frags, chunks 0..2 (!XIN)

    if constexpr (XIN) {
        // 16*HR row-tasks (ci16, iy in halo): fp32 NCHW, bounds-checked
        for (int task = tid; task < 16 * HR; task += 256) {
            int ci = task / HR, iy = task - (task / HR) * HR;
            float v[18];
#pragma unroll
            for (int ix = 0; ix < 18; ++ix) v[ix] = 0.f;
            int gy = y0 + iy - 1;
            if ((unsigned)gy < (unsigned)HW) {
                const float* rp = xsrc + (((size_t)b * 16 + ci) * HW + gy) * HW + x0;
                f32x4 q0 = *(const f32x4*)(rp);
                f32x4 q1 = *(const f32x4*)(rp + 4);
                f32x4 q2 = *(const f32x4*)(rp + 8);
                f32x4 q3 = *(const f32x4*)(rp + 12);
#pragma unroll
                for (int j = 0; j < 4; ++j) {
                    v[1 + j] = q0[j]; v[5 + j] = q1[j];
                    v[9 + j] = q2[j]; v[13 + j] = q3[j];
                }
                if (x0 > 0)       v[0]  = rp[-1];
                if (x0 < HW - 16) v[17] = rp[16];
            }
            int cg = ci >> 3, cj = ci & 7;
#pragma unroll
            for (int ix = 0; ix < 18; ++ix)
                xh[(((iy * 2 + cg) * 18) + ix) * 8 + cj] = (_Float16)v[ix];
        }
        __syncthreads();
    } else {
        const _Float16* const ins[3] = {P.in0, P.in1, P.in2};
        auto stage = [&](int s) {
            // tile halo origin in padded coords = (by*ROWS, bx*16)
            const _Float16* src = ins[s] + (size_t)b * (PW * PW * 16)
                                 + ((size_t)y0 * PW + bx * 16) * 16;
            _Float16* base = xh + s * SLTH;
#pragma unroll
            for (int k = 0; k < 3; ++k) {
                int kk = wv + k * 4;
                if (kk < KBLK) {            // wave-uniform
                    int u = kk * 64 + lane;
                    int iy = u / 36, r36 = u - iy * 36;
                    int cg = r36 / 18, ix = r36 - cg * 18;
                    GLD_LDS(src + (iy * PW + ix) * 16 + cg * 8, base + kk * 512);
                }
            }
        };
        // Preload FIRST: oldest VMEM ops -> counted DMA wait covers them.
#pragma unroll
        for (int cot = 0; cot < 3; ++cot) {
            if (!(LIVE & (1 << cot))) continue;
#pragma unroll
            for (int r = 0; r < 4; ++r) bv[cot][r] = P.bc[cot * 16 + quad * 4 + r];
        }
        {
            const _Float16* As0 = P.Ac + quad * 384 + n * 8;
#pragma unroll
            for (int c = 0; c < 3; ++c)
#pragma unroll
                for (int cot = 0; cot < 3; ++cot) {
                    if (!(LIVE & (1 << cot))) continue;
                    a0[c][cot] = *(const half8*)(As0 + c * 1536 + cot * 128);
                }
        }
        asm volatile("" ::: "memory");   // keep preloads ahead of the DMAs
        stage(0);
        if constexpr (NIN >= 2) {
            asm volatile("" ::: "memory");
#pragma unroll
            for (int s = 1; s < NIN; ++s) stage(s);
            // own slot0 DMA retired when <= (NIN-1)*C outstanding
            if constexpr (ROWS == 16) {
                if (wv == 3) asm volatile("s_waitcnt vmcnt(%0)" :: "n"((NIN - 1) * 2) : "memory");
                else         asm volatile("s_waitcnt vmcnt(%0)" :: "n"((NIN - 1) * 3) : "memory");
            } else {
                if (wv < 2)  asm volatile("s_waitcnt vmcnt(%0)" :: "n"((NIN - 1) * 2) : "memory");
                else         asm volatile("s_waitcnt vmcnt(%0)" :: "n"((NIN - 1) * 1) : "memory");
            }
            __builtin_amdgcn_s_barrier();   // -> all waves' slot0 retired
            asm volatile("" ::: "memory");
        } else {
            __syncthreads();
        }
    }

    // Per-chunk B-read base unit. Dead groups (g>=18) -> g=0 (A zero there).
    int base_c[5];
#pragma unroll
    for (int c = 0; c < 5; ++c) {
        int g = c * 4 + quad;
        if (g >= 18) g = 0;
        int kh = g / 6, r6 = g % 6;
        int kw = r6 >> 1, cg = r6 & 1;
        base_c[c] = ((py0 + kh) * 2 + cg) * 18 + n + kw;
    }

    // acc[cot][nt]: co = cot*16 + quad*4 + r, pixel (y0+py0+nt, x0+n)
    constexpr bool PIPE = (!XIN) && (NIN >= 2);
    f32x4 acc[3][NT];
#pragma unroll
    for (int cot = 0; cot < 3; ++cot) {
        if (!(LIVE & (1 << cot))) continue;
#pragma unroll
        for (int r = 0; r < 4; ++r) {
            float bvv = XIN ? P.bc[cot * 16 + quad * 4 + r] : bv[cot][r];
#pragma unroll
            for (int nt = 0; nt < NT; ++nt) acc[cot][nt][r] = bvv;
        }
    }

    // ---- K loop: flattened NIN*5 chunk schedule, fully unrolled ----
    // PIPE order: s0c0..2 | barrier | s1(,s2) all | s0c3,c4.
    constexpr int NC = NIN * 5;
#pragma unroll
    for (int i = 0; i < NC; ++i) {
        int s, c;
        if constexpr (PIPE) {
            if (i < 3)                        { s = 0; c = i; }
            else if (i < 3 + 5 * (NIN - 1))   { s = 1 + (i - 3) / 5; c = (i - 3) % 5; }
            else                              { s = 0; c = i - 5 * (NIN - 1); }
        } else { s = i / 5; c = i % 5; }
        if (PIPE && i == 3) __syncthreads();   // slots 1.. ready (full drain)

        const _Float16* sxh = xh + s * (XIN ? 0 : ((ROWS == 16) ? 5632 : 3072));
        half8 Bh[NT];
#pragma unroll
        for (int nt = 0; nt < NT; ++nt)
            Bh[nt] = *(const half8*)(sxh + (base_c[c] + nt * 36) * 8);
        const _Float16* Ab = P.Ac + (size_t)(s * 5 + c) * 1536 + quad * 384 + n * 8;
        half8 ah[3];
#pragma unroll
        for (int cot = 0; cot < 3; ++cot) {
            if (!(LIVE & (1 << cot))) continue;
            if (!XIN && s == 0 && c < 3) ah[cot] = a0[c][cot];
            else                         ah[cot] = *(const half8*)(Ab + cot * 128);
        }
        __builtin_amdgcn_s_setprio(1);
#pragma unroll
        for (int cot = 0; cot < 3; ++cot) {
            if (!(LIVE & (1 << cot))) continue;
#pragma unroll
            for (int nt = 0; nt < NT; ++nt)
                acc[cot][nt] = __builtin_amdgcn_mfma_f32_16x16x32_f16(ah[cot], Bh[nt], acc[cot][nt], 0, 0, 0);
        }
        __builtin_amdgcn_s_setprio(0);
    }

    // ---- epilogue ----
    if constexpr (FIN) {
        // final cell: fp32 NCHW scatter to d_out (validated path)
#pragma unroll
        for (int nt = 0; nt < NT; ++nt) {
            int y = y0 + py0 + nt, xg = x0 + n;
#pragma unroll
            for (int r = 0; r < 4; ++r) {
                float vv = acc[0][nt][r];
                P.fout[(((size_t)b * 16 + quad * 4 + r) * HW + y) * HW + xg] = vv > 0.f ? vv : 0.f;
            }
        }
    } else {
        // fp16 NHWC stores into padded interior (+1,+1)
        _Float16* const outs[3] = {P.o0, P.o1, P.o2};
#pragma unroll
        for (int cot = 0; cot < 3; ++cot) {
            if (!(LIVE & (1 << cot))) continue;
            _Float16* op = outs[cot] + (size_t)b * (PW * PW * 16);
#pragma unroll
            for (int nt = 0; nt < NT; ++nt) {
                int y = y0 + py0 + nt;
                half4 hv;
#pragma unroll
                for (int r = 0; r < 4; ++r) {
                    float vv = acc[cot][nt][r];
                    hv[r] = (_Float16)(vv > 0.f ? vv : 0.f);
                }
                *(half4*)(op + ((size_t)(y + 1) * PW + x0 + n + 1) * 16 + quad * 4) = hv;
            }
        }
    }
}

// ---------------------------------------------------------------------------
// Stage kernel: one or two independent cells per launch. blockIdx.z < 8 ->
// cell 0 (batch z), z >= 8 -> cell 1 (batch z-8, always ROWS=16). R0 = tile
// height for cell 0. LDS sized for the max of both paths.
// ---------------------------------------------------------------------------
template<int L0, int N0, int L1, int N1, bool FIN, bool XIN, int R0>
__global__ __launch_bounds__(256, 4) void cell_k(CellIO P0, CellIO P1,
                                                 const float* xsrc) {
    constexpr int slotR = (R0 == 16) ? 5632 : 3072;
    constexpr int ldsA  = XIN ? ((R0 + 2) * 2 * 18 * 8) : (N0 * slotR);
    constexpr int ldsB  = (L1 > 0) ? (N1 * 5632) : 0;
    constexpr int LDSH  = (ldsA > ldsB) ? ldsA : ldsB;
    __shared__ __align__(16) _Float16 xh[LDSH];
    int b = blockIdx.z & 7;
    if constexpr (L1 > 0) {
        if (blockIdx.z >= 8) { cell_body<L1, N1, false, false, 16>(P1, b, xh, nullptr); return; }
    }
    cell_body<L0, N0, FIN, XIN, R0>(P0, b, xh, xsrc);
}

// ---------------------------------------------------------------------------
// Orchestration: anti-diagonal stage schedule s = 2*col + row (validated r5;
// depth-10 is the exact dependency-graph longest path — launch-minimal).
// Buffers: padded 130x130 fp16 NHWC (4.33 MB): R[colpar][row] x8, U[1..3] x3,
// D[2][2] x4. Cell (0,0) reads fp32 x directly.
//
// Structural plateau notes: cross-XCD flag dataflow (r14) and cooperative
// launch (r17) fail; head-fusion fails all three ways (r23 inline, r24
// mega, r28 fine-backfill: ~+5us each); direct-B without LDS staging
// +10us (r26). 10 stage launches + 1 head node is the legal minimum.
//
// DETERMINISM ARMOR (r18/r19): harness re-poisons d_ws 0xAA each call; the
// border ring is the only stream region read-but-never-written per call, so
// ring-only zeroing (fused into the head launch) keeps replay bit-identical
// (r19 validated). Staging over-DMA reads at most 7.8 KB (ROWS=16) / 4.1 KB
// (ROWS=8) past the last stream buffer — inside ws slack (poisoned, unread).
// ---------------------------------------------------------------------------
extern "C" void kernel_launch(void* const* d_in, const int* in_sizes, int n_in,
                              void* d_out, int out_size, void* d_ws, size_t ws_size,
                              hipStream_t stream) {
    const float* x  = (const float*)d_in[0];   // [8,16,128,128]
    const float* W  = (const float*)d_in[1];   // [4,4,48,48,3,3]
    const float* bi = (const float*)d_in[2];   // [4,4,48]
    float* out = (float*)d_out;                // [8,16,128,128]

    _Float16* Abuf = (_Float16*)d_ws;
    const size_t abytes = (size_t)NCELL * ABUF_PER_CELL * 2;   // 0.74 MB
    _Float16* q = (_Float16*)((char*)d_ws + abytes);
    _Float16* sbase = q;                                       // stream region base
    const size_t S = (size_t)8 * PW * PW * 16;                 // halfs/buffer

    _Float16 *R[2][4], *U[4], *D[2][2];
    for (int pa = 0; pa < 2; ++pa)
        for (int r = 0; r < 4; ++r) { R[pa][r] = q; q += S; }
    U[0] = nullptr;
    for (int r = 1; r < 4; ++r) { U[r] = q; q += S; }
    D[0][0] = q; q += S; D[0][1] = q; q += S;
    D[1][0] = q; q += S; D[1][1] = q; q += S;

    // Fused head launch: weight prep + border-ring zero
    hipLaunchKernelGGL(prep_w_border_k,
                       dim3((ABUF_TOTAL + BORDER_TASKS + 255) / 256),
                       dim3(256), 0, stream, W, Abuf, sbase);

    auto mkio = [&](int c, int r) -> CellIO {
        CellIO io{};
        if (c == 0) {
            io.in0 = (r == 0) ? nullptr : D[0][(r - 1) & 1];   // r==0: XIN
        } else {
            io.in0 = R[(c - 1) & 1][r];
            if (r == 0)      io.in1 = U[1];
            else if (r == 3) io.in1 = D[c & 1][0];
            else { io.in1 = U[r + 1]; io.in2 = D[c & 1][(r - 1) & 1]; }
        }
        if (c < 3) {
            io.o0 = R[c & 1][r];
            if (r > 0) io.o1 = U[r];
            if (r < 3) io.o2 = D[c & 1][r & 1];
        } else {
            if (r < 3) io.o2 = D[1][r & 1];
            else       io.fout = out;
        }
        io.Ac = Abuf + (size_t)(c * 4 + r) * ABUF_PER_CELL;
        io.bc = bi + (size_t)(c * 4 + r) * 48;
        return io;
    };

    dim3 blk(256), g2(8, 8, 16), g8(8, 16, 8);
#define ONEX(c, r)       do { CellIO a = mkio(c, r); \
    hipLaunchKernelGGL((cell_k<5, 1, 0, 0, false, true, 8>), g8, blk, 0, stream, a, a, x); } while (0)
#define ONE(L, N, c, r)  do { CellIO a = mkio(c, r); \
    hipLaunchKernelGGL((cell_k<L, N, 0, 0, false, false, 8>), g8, blk, 0, stream, a, a, x); } while (0)
#define ONEF(c, r)       do { CellIO a = mkio(c, r); \
    hipLaunchKernelGGL((cell_k<1, 2, 0, 0, true, false, 8>), g8, blk, 0, stream, a, a, x); } while (0)
#define TWO(L0, N0, c0, r0, L1, N1, c1, r1) do { \
    CellIO a = mkio(c0, r0), bb2 = mkio(c1, r1); \
    hipLaunchKernelGGL((cell_k<L0, N0, L1, N1, false, false, 16>), g2, blk, 0, stream, a, bb2, x); } while (0)

    ONEX(0, 0);
    ONE(7, 1, 0, 1);
    TWO(7, 1, 0, 2,  5, 2, 1, 0);
    TWO(3, 1, 0, 3,  7, 3, 1, 1);
    TWO(7, 3, 1, 2,  5, 2, 2, 0);
    TWO(3, 2, 1, 3,  7, 3, 2, 1);
    TWO(7, 3, 2, 2,  4, 2, 3, 0);
    TWO(3, 2, 2, 3,  4, 3, 3, 1);
    ONE(4, 3, 3, 2);
    ONEF(3, 3);
#undef ONEX
#undef ONE
#undef ONEF
#undef TWO
}